// Round 1
// baseline (867.455 us; speedup 1.0000x reference)
//
#include <hip/hip_runtime.h>
#include <math.h>

// Problem constants (fixed by the reference)
#define NNODES 262144
#define BATCH  64
#define CD     320      // C*D = 5*64 flattened features per plane
#define NPLANE 3
#define NCHUNK 8        // node-chunks per segment (grid.x)
#define TY     8        // node-parallel rows per block (blockDim.y)
#define NEG_BIG (-3.0e38f)

// Uniform binary search: first index with a[i] >= key (batch array is sorted).
__device__ __forceinline__ int lower_bound_dev(const int* __restrict__ a, int n, int key) {
    int lo = 0, hi = n;
    while (lo < hi) {
        int mid = (lo + hi) >> 1;
        if (a[mid] < key) lo = mid + 1; else hi = mid;
    }
    return lo;
}

// Merge online-softmax state (m,d,n) <- (m2,d2,n2).
// Uses exp(-|m-m2|) so -3e38 sentinels never produce inf-inf NaN.
__device__ __forceinline__ void combine_state(float& m, float& d, float& n,
                                              float m2, float d2, float n2) {
    float M  = fmaxf(m, m2);
    float p  = __expf(-fabsf(m - m2));
    bool  ge = (m >= m2);
    float s1 = ge ? 1.0f : p;
    float s2 = ge ? p : 1.0f;
    d = d * s1 + d2 * s2;
    n = n * s1 + n2 * s2;
    m = M;
}

// Kernel 1: per (plane, segment, chunk) partial online softmax over all 320 features.
// block (64, TY); thread owns 5 feature columns f = tx + 64*j.
// part layout: [plane][b][chunk][3(m,d,n)][CD]
__global__ __launch_bounds__(512)
void seg_softmax_partial(const float* __restrict__ m_u, const int* __restrict__ b_u, const float* __restrict__ t_u,
                         const float* __restrict__ m_v, const int* __restrict__ b_v, const float* __restrict__ t_v,
                         const float* __restrict__ m_y, const int* __restrict__ b_y, const float* __restrict__ t_y,
                         float* __restrict__ part)
{
    const int c     = blockIdx.x;   // chunk
    const int bseg  = blockIdx.y;   // segment id
    const int plane = blockIdx.z;

    const float* x; const int* idx; float tval;
    if (plane == 0)      { x = m_u; idx = b_u; tval = t_u[0]; }
    else if (plane == 1) { x = m_v; idx = b_v; tval = t_v[0]; }
    else                 { x = m_y; idx = b_y; tval = t_y[0]; }

    const int start = lower_bound_dev(idx, NNODES, bseg);
    const int end   = lower_bound_dev(idx, NNODES, bseg + 1);

    const int tx = threadIdx.x;     // 0..63
    const int ty = threadIdx.y;     // 0..TY-1

    float m[5], d[5], n[5];
    #pragma unroll
    for (int j = 0; j < 5; ++j) { m[j] = NEG_BIG; d[j] = 0.f; n[j] = 0.f; }

    // Strided streaming over this segment's rows. One wave reads the full
    // contiguous 1280 B row via 5 coalesced dword loads.
    for (int i = start + c * TY + ty; i < end; i += NCHUNK * TY) {
        const float* row = x + (size_t)i * CD + tx;
        float xv[5];
        #pragma unroll
        for (int j = 0; j < 5; ++j) xv[j] = row[j * 64];   // issue all loads first
        #pragma unroll
        for (int j = 0; j < 5; ++j) {
            float s  = tval * xv[j];
            float p  = __expf(-fabsf(s - m[j]));           // exp(-|s-m|): single exp/elem
            bool  gt = (s > m[j]);
            float scale = gt ? p : 1.0f;                   // rescale old state
            float e     = gt ? 1.0f : p;                   // weight of new elem
            m[j] = fmaxf(m[j], s);
            d[j] = d[j] * scale + e;
            n[j] = n[j] * scale + e * xv[j];
        }
    }

    // Reduce TY node-rows -> one state per feature, via LDS.
    __shared__ float sm[TY][CD];   // 8*320*4 = 10240 B each, 30720 B total
    __shared__ float sd[TY][CD];
    __shared__ float sn[TY][CD];
    #pragma unroll
    for (int j = 0; j < 5; ++j) {
        sm[ty][tx + 64 * j] = m[j];
        sd[ty][tx + 64 * j] = d[j];
        sn[ty][tx + 64 * j] = n[j];
    }
    __syncthreads();

    const int lin = ty * 64 + tx;   // 0..511
    if (lin < CD) {
        float M = sm[0][lin], D = sd[0][lin], Nn = sn[0][lin];
        #pragma unroll
        for (int r = 1; r < TY; ++r)
            combine_state(M, D, Nn, sm[r][lin], sd[r][lin], sn[r][lin]);
        size_t base = ((((size_t)plane * BATCH + bseg) * NCHUNK + c) * 3) * CD + lin;
        part[base]          = M;
        part[base + CD]     = D;
        part[base + 2 * CD] = Nn;
    }
}

// Kernel 2: merge NCHUNK partials per (plane, segment, feature) and emit
// feat[b][plane*CD + f] = n/d (0 for empty segments).
__global__ __launch_bounds__(CD)
void merge_feat(const float* __restrict__ part, float* __restrict__ feat)
{
    const int f     = threadIdx.x;  // 0..319
    const int bseg  = blockIdx.x;   // 0..63
    const int plane = blockIdx.y;   // 0..2

    size_t base = ((((size_t)plane * BATCH + bseg) * NCHUNK) * 3) * CD + f;
    float M = part[base], D = part[base + CD], Nn = part[base + 2 * CD];
    #pragma unroll
    for (int cidx = 1; cidx < NCHUNK; ++cidx) {
        size_t b2 = base + (size_t)cidx * 3 * CD;
        combine_state(M, D, Nn, part[b2], part[b2 + CD], part[b2 + 2 * CD]);
    }
    float out = (D > 0.f) ? (Nn / D) : 0.f;
    feat[(size_t)bseg * (NPLANE * CD) + plane * CD + f] = out;
}

// Kernel 3: tiny decode — out[b][e] = feat[b][:] . W[e][:] + bias[e].
// 192 outputs; feat (245 KB) and W are L2-resident. float4 loads, 4 accumulators.
__global__ __launch_bounds__(192)
void decode_out(const float* __restrict__ feat, const float* __restrict__ W,
                const float* __restrict__ bias, float* __restrict__ out)
{
    const int tid  = threadIdx.x;       // 0..191
    const int bseg = tid / 3;
    const int e    = tid % 3;
    const float4* fr = (const float4*)(feat + (size_t)bseg * (NPLANE * CD));
    const float4* wr = (const float4*)(W    + (size_t)e    * (NPLANE * CD));
    float a0 = 0.f, a1 = 0.f, a2 = 0.f, a3 = 0.f;
    #pragma unroll 4
    for (int q = 0; q < (NPLANE * CD) / 16; ++q) {
        float4 f0 = fr[4 * q + 0], w0 = wr[4 * q + 0];
        float4 f1 = fr[4 * q + 1], w1 = wr[4 * q + 1];
        float4 f2 = fr[4 * q + 2], w2 = wr[4 * q + 2];
        float4 f3 = fr[4 * q + 3], w3 = wr[4 * q + 3];
        a0 += f0.x * w0.x + f0.y * w0.y + f0.z * w0.z + f0.w * w0.w;
        a1 += f1.x * w1.x + f1.y * w1.y + f1.z * w1.z + f1.w * w1.w;
        a2 += f2.x * w2.x + f2.y * w2.y + f2.z * w2.z + f2.w * w2.w;
        a3 += f3.x * w3.x + f3.y * w3.y + f3.z * w3.z + f3.w * w3.w;
    }
    out[tid] = (a0 + a1) + (a2 + a3) + bias[e];
}

extern "C" void kernel_launch(void* const* d_in, const int* in_sizes, int n_in,
                              void* d_out, int out_size, void* d_ws, size_t ws_size,
                              hipStream_t stream)
{
    // setup_inputs() order: m_u, batch_u, t_u, m_v, batch_v, t_v, m_y, batch_y, t_y, W, b
    const float* m_u = (const float*)d_in[0];
    const int*   b_u = (const int*)  d_in[1];
    const float* t_u = (const float*)d_in[2];
    const float* m_v = (const float*)d_in[3];
    const int*   b_v = (const int*)  d_in[4];
    const float* t_v = (const float*)d_in[5];
    const float* m_y = (const float*)d_in[6];
    const int*   b_y = (const int*)  d_in[7];
    const float* t_y = (const float*)d_in[8];
    const float* W   = (const float*)d_in[9];
    const float* bia = (const float*)d_in[10];
    float* out = (float*)d_out;

    // Workspace: partial states (5.9 MB) + feat (245 KB)
    float* part = (float*)d_ws;                                   // [3][64][8][3][320]
    float* feat = part + (size_t)NPLANE * BATCH * NCHUNK * 3 * CD; // [64][960]

    dim3 g1(NCHUNK, BATCH, NPLANE), b1(64, TY);
    seg_softmax_partial<<<g1, b1, 0, stream>>>(m_u, b_u, t_u, m_v, b_v, t_v,
                                               m_y, b_y, t_y, part);

    dim3 g2(BATCH, NPLANE), b2(CD);
    merge_feat<<<g2, b2, 0, stream>>>(part, feat);

    decode_out<<<1, 192, 0, stream>>>(feat, W, bia, out);
}